// Round 4
// baseline (21241.859 us; speedup 1.0000x reference)
//
#include <hip/hip_runtime.h>

#define LSTM_B   4096
#define LSTM_H   1024
#define LSTM_IN  512
#define LSTM_OUT 512

typedef unsigned long long u64;
typedef unsigned int u32;

__device__ __forceinline__ u64 aload(u64* p) {
  return __hip_atomic_load(p, __ATOMIC_RELAXED, __HIP_MEMORY_SCOPE_AGENT);
}
__device__ __forceinline__ void astore(u64* p, u64 v) {
  __hip_atomic_store(p, v, __ATOMIC_RELAXED, __HIP_MEMORY_SCOPE_AGENT);
}
__device__ __forceinline__ u64 packft(float f, u32 tag) {
  return ((u64)tag << 32) | (u64)__float_as_uint(f);
}
__device__ __forceinline__ float dot4f(float4 a, float4 b) {
  return fmaf(a.x, b.x, fmaf(a.y, b.y, fmaf(a.z, b.z, a.w * b.w)));
}
// fast activations: v_exp_f32 + v_rcp_f32. |rel err| ~1e-6, bounded outputs.
__device__ __forceinline__ float fsig(float x) {
  return __builtin_amdgcn_rcpf(1.0f + __expf(-x));
}
__device__ __forceinline__ float ftanh(float x) {
  return 1.0f - 2.0f * __builtin_amdgcn_rcpf(1.0f + __expf(2.0f * x));
}

// ---- AGPR parking: weights live in the accumulator half of the unified RF.
// park4: VGPR->AGPR once at init. fetch4: AGPR->VGPR each use, asm volatile so
// it can't be hoisted (loop-invariant!) or turned back into a memory load.
__device__ __forceinline__ void park4(float4& a, float4 v) {
  asm volatile("v_accvgpr_write_b32 %0, %4\n\t"
               "v_accvgpr_write_b32 %1, %5\n\t"
               "v_accvgpr_write_b32 %2, %6\n\t"
               "v_accvgpr_write_b32 %3, %7"
               : "=a"(a.x), "=a"(a.y), "=a"(a.z), "=a"(a.w)
               : "v"(v.x), "v"(v.y), "v"(v.z), "v"(v.w));
}
__device__ __forceinline__ float4 fetch4(const float4& a) {
  float4 r;
  asm volatile("v_accvgpr_read_b32 %0, %4\n\t"
               "v_accvgpr_read_b32 %1, %5\n\t"
               "v_accvgpr_read_b32 %2, %6\n\t"
               "v_accvgpr_read_b32 %3, %7"
               : "=v"(r.x), "=v"(r.y), "=v"(r.z), "=v"(r.w)
               : "a"(a.x), "a"(a.y), "a"(a.z), "a"(a.w));
  return r;
}

// ---------------- transpose fc_w [512,1024] -> fcwT [1024,512] ----------------
__global__ void k_transpose(const float* __restrict__ w, float* __restrict__ wT) {
  int idx = blockIdx.x * 256 + threadIdx.x;   // 512*1024 total
  int k = idx >> 9;
  int o = idx & 511;
  wT[idx] = w[o * 1024 + k];
}

// ---------------- persistent recurrent kernel ----------------
// 256 blocks x 512 threads (8 waves, 2/SIMD). Block bx owns units 4bx..4bx+3.
// Waves 0-3: layer1 unit j=w -> 128 weight floats in AGPRs.
// Waves 4-7: layer0 unit j=w-4 -> 96 weight floats in AGPRs.
// Butterfly all-reduce -> gates SIMD-wide, lane0 stores packed (tag|fp32).
// One barrier per phase. Phase t: layer1(t) + layer0(t+1).
__global__ __launch_bounds__(512)
__attribute__((amdgpu_waves_per_eu(2, 2)))
void k_recur(
    const float* __restrict__ x,
    const float* __restrict__ Whh0, const float* __restrict__ Wih0,
    const float* __restrict__ bih0, const float* __restrict__ bhh0,
    const float* __restrict__ Wih1, const float* __restrict__ Whh1,
    const float* __restrict__ bih1, const float* __restrict__ bhh1,
    const float* __restrict__ h0in, const float* __restrict__ c0in,
    u64* __restrict__ h0buf, u64* __restrict__ h1buf)
{
  __shared__ float h0s[2][LSTM_H];
  __shared__ float h1s[2][LSTM_H];
  __shared__ float xs[2][LSTM_IN];

  const int tid = threadIdx.x;           // 0..511
  const int w = tid >> 6, l = tid & 63;
  const int bx = blockIdx.x;
  const int j = w & 3;
  const int hd = 4 * bx + j;

  // prologue LDS: h0 init (phase -1 uses buffer 1), x[0]
  h0s[1][tid]       = h0in[tid];
  h0s[1][tid + 512] = h0in[tid + 512];
  xs[1][tid & 511]  = x[tid & 511];

  if (w < 4) {
    // ================= layer-1 waves =================
    float4 Wi[4][4], Wh[4][4];   // AGPR-resident (park4/fetch4 only)
#pragma unroll
    for (int g = 0; g < 4; ++g)
#pragma unroll
      for (int q = 0; q < 4; ++q) {
        park4(Wi[g][q], *(const float4*)&Wih1[(size_t)(g * 1024 + hd) * 1024 + q * 256 + 4 * l]);
        park4(Wh[g][q], *(const float4*)&Whh1[(size_t)(g * 1024 + hd) * 1024 + q * 256 + 4 * l]);
      }
    float bsum[4];
#pragma unroll
    for (int g = 0; g < 4; ++g) bsum[g] = bih1[g * 1024 + hd] + bhh1[g * 1024 + hd];
    float c = c0in[1024 + hd];

    __syncthreads();  // prologue barrier (matches other branch)
    if (l == 0) astore(&h1buf[hd], packft(h0in[1024 + hd], 0u));  // seed h1(init) step 0

    u64* p0 = &h0buf[tid];
    u64* p1 = &h1buf[tid];
#pragma unroll 1
    for (int t = 0; t < LSTM_B; ++t, p0 += 1024, p1 += 1024) {
      const int buf = t & 1;
      const u32 tt = (u32)t;
      // ---- concurrent poll of all 4 slots: one RTT per round
      u64 v0a, v0b, v1a, v1b;
      for (;;) {
        v0a = aload(p0); v0b = aload(p0 + 512);
        v1a = aload(p1); v1b = aload(p1 + 512);
        if (((u32)(v0a >> 32) == tt) & ((u32)(v0b >> 32) == tt) &
            ((u32)(v1a >> 32) == tt) & ((u32)(v1b >> 32) == tt)) break;
        __builtin_amdgcn_s_sleep(1);
      }
      h0s[buf][tid]       = __uint_as_float((u32)v0a);
      h0s[buf][tid + 512] = __uint_as_float((u32)v0b);
      h1s[buf][tid]       = __uint_as_float((u32)v1a);
      h1s[buf][tid + 512] = __uint_as_float((u32)v1b);
      __syncthreads();

      float a0 = 0.f, a1 = 0.f, a2 = 0.f, a3 = 0.f;
#pragma unroll
      for (int q = 0; q < 4; ++q) {
        float4 h0q = *(const float4*)&h0s[buf][q * 256 + 4 * l];
        float4 h1q = *(const float4*)&h1s[buf][q * 256 + 4 * l];
        { float4 u = fetch4(Wi[0][q]); a0 += dot4f(u, h0q); u = fetch4(Wh[0][q]); a0 += dot4f(u, h1q); }
        { float4 u = fetch4(Wi[1][q]); a1 += dot4f(u, h0q); u = fetch4(Wh[1][q]); a1 += dot4f(u, h1q); }
        { float4 u = fetch4(Wi[2][q]); a2 += dot4f(u, h0q); u = fetch4(Wh[2][q]); a2 += dot4f(u, h1q); }
        { float4 u = fetch4(Wi[3][q]); a3 += dot4f(u, h0q); u = fetch4(Wh[3][q]); a3 += dot4f(u, h1q); }
      }
#pragma unroll
      for (int m = 1; m < 64; m <<= 1) {
        a0 += __shfl_xor(a0, m, 64);
        a1 += __shfl_xor(a1, m, 64);
        a2 += __shfl_xor(a2, m, 64);
        a3 += __shfl_xor(a3, m, 64);
      }
      c = fsig(a1 + bsum[1]) * c + fsig(a0 + bsum[0]) * ftanh(a2 + bsum[2]);
      float hn = fsig(a3 + bsum[3]) * ftanh(c);
      if (l == 0) astore(&h1buf[(size_t)(t + 1) * 1024 + hd], packft(hn, tt + 1));
    }
  } else {
    // ================= layer-0 waves =================
    float4 Whr[4][4], Wxr[4][2];  // AGPR-resident
#pragma unroll
    for (int g = 0; g < 4; ++g) {
#pragma unroll
      for (int q = 0; q < 4; ++q)
        park4(Whr[g][q], *(const float4*)&Whh0[(size_t)(g * 1024 + hd) * 1024 + q * 256 + 4 * l]);
#pragma unroll
      for (int q = 0; q < 2; ++q)
        park4(Wxr[g][q], *(const float4*)&Wih0[(size_t)(g * 1024 + hd) * 512 + q * 256 + 4 * l]);
    }
    float bsum[4];
#pragma unroll
    for (int g = 0; g < 4; ++g) bsum[g] = bih0[g * 1024 + hd] + bhh0[g * 1024 + hd];
    float c = c0in[hd];

    __syncthreads();  // prologue barrier
    {
      // prologue compute: layer0 step 0 from h0 init (buffer 1) and x[0]
      float a0 = 0.f, a1 = 0.f, a2 = 0.f, a3 = 0.f;
#pragma unroll
      for (int q = 0; q < 4; ++q) {
        float4 hq = *(const float4*)&h0s[1][q * 256 + 4 * l];
        { float4 u = fetch4(Whr[0][q]); a0 += dot4f(u, hq); }
        { float4 u = fetch4(Whr[1][q]); a1 += dot4f(u, hq); }
        { float4 u = fetch4(Whr[2][q]); a2 += dot4f(u, hq); }
        { float4 u = fetch4(Whr[3][q]); a3 += dot4f(u, hq); }
      }
#pragma unroll
      for (int q = 0; q < 2; ++q) {
        float4 xq = *(const float4*)&xs[1][q * 256 + 4 * l];
        { float4 u = fetch4(Wxr[0][q]); a0 += dot4f(u, xq); }
        { float4 u = fetch4(Wxr[1][q]); a1 += dot4f(u, xq); }
        { float4 u = fetch4(Wxr[2][q]); a2 += dot4f(u, xq); }
        { float4 u = fetch4(Wxr[3][q]); a3 += dot4f(u, xq); }
      }
#pragma unroll
      for (int m = 1; m < 64; m <<= 1) {
        a0 += __shfl_xor(a0, m, 64);
        a1 += __shfl_xor(a1, m, 64);
        a2 += __shfl_xor(a2, m, 64);
        a3 += __shfl_xor(a3, m, 64);
      }
      c = fsig(a1 + bsum[1]) * c + fsig(a0 + bsum[0]) * ftanh(a2 + bsum[2]);
      float hn = fsig(a3 + bsum[3]) * ftanh(c);
      if (l == 0) astore(&h0buf[hd], packft(hn, 0u));
    }

    const int xi = tid - 256;  // 0..255
    u64* p0 = &h0buf[tid];
    u64* p1 = &h1buf[tid];
#pragma unroll 1
    for (int t = 0; t < LSTM_B; ++t, p0 += 1024, p1 += 1024) {
      const int buf = t & 1;
      const u32 tt = (u32)t;
      // x(t+1) prefetch issued before polling (latency hidden by poll)
      float xv0 = 0.f, xv1 = 0.f;
      if (t + 1 < LSTM_B) {
        xv0 = x[(size_t)(t + 1) * 512 + xi];
        xv1 = x[(size_t)(t + 1) * 512 + xi + 256];
      }
      u64 v0a, v0b, v1a, v1b;
      for (;;) {
        v0a = aload(p0); v0b = aload(p0 + 512);
        v1a = aload(p1); v1b = aload(p1 + 512);
        if (((u32)(v0a >> 32) == tt) & ((u32)(v0b >> 32) == tt) &
            ((u32)(v1a >> 32) == tt) & ((u32)(v1b >> 32) == tt)) break;
        __builtin_amdgcn_s_sleep(1);
      }
      h0s[buf][tid]       = __uint_as_float((u32)v0a);
      h0s[buf][tid + 512] = __uint_as_float((u32)v0b);
      h1s[buf][tid]       = __uint_as_float((u32)v1a);
      h1s[buf][tid + 512] = __uint_as_float((u32)v1b);
      xs[buf][xi]         = xv0;
      xs[buf][xi + 256]   = xv1;
      __syncthreads();

      float a0 = 0.f, a1 = 0.f, a2 = 0.f, a3 = 0.f;
#pragma unroll
      for (int q = 0; q < 4; ++q) {
        float4 hq = *(const float4*)&h0s[buf][q * 256 + 4 * l];
        { float4 u = fetch4(Whr[0][q]); a0 += dot4f(u, hq); }
        { float4 u = fetch4(Whr[1][q]); a1 += dot4f(u, hq); }
        { float4 u = fetch4(Whr[2][q]); a2 += dot4f(u, hq); }
        { float4 u = fetch4(Whr[3][q]); a3 += dot4f(u, hq); }
      }
#pragma unroll
      for (int q = 0; q < 2; ++q) {
        float4 xq = *(const float4*)&xs[buf][q * 256 + 4 * l];
        { float4 u = fetch4(Wxr[0][q]); a0 += dot4f(u, xq); }
        { float4 u = fetch4(Wxr[1][q]); a1 += dot4f(u, xq); }
        { float4 u = fetch4(Wxr[2][q]); a2 += dot4f(u, xq); }
        { float4 u = fetch4(Wxr[3][q]); a3 += dot4f(u, xq); }
      }
#pragma unroll
      for (int m = 1; m < 64; m <<= 1) {
        a0 += __shfl_xor(a0, m, 64);
        a1 += __shfl_xor(a1, m, 64);
        a2 += __shfl_xor(a2, m, 64);
        a3 += __shfl_xor(a3, m, 64);
      }
      c = fsig(a1 + bsum[1]) * c + fsig(a0 + bsum[0]) * ftanh(a2 + bsum[2]);
      float hn = fsig(a3 + bsum[3]) * ftanh(c);
      if (l == 0 && t + 1 < LSTM_B)
        astore(&h0buf[(size_t)(t + 1) * 1024 + hd], packft(hn, tt + 1));
    }
  }
}

// ---------------- FC + softmax: 16 timesteps per block ----------------
__global__ __launch_bounds__(256) void k_fc(u64* __restrict__ h1buf,
                                            const float* __restrict__ fcwT,
                                            const float* __restrict__ fcb,
                                            float* __restrict__ out) {
  __shared__ float smem[16 * 1024];
  const int tid = threadIdx.x;
  const int t0 = blockIdx.x * 16;

  for (int i = 0; i < 64; ++i) {
    int e = tid + 256 * i;
    int tt = e >> 10, k = e & 1023;
    u64 v = aload(&h1buf[(size_t)(t0 + tt + 1) * 1024 + k]);
    smem[e] = __uint_as_float((u32)v);
  }
  __syncthreads();

  float acc0[16], acc1[16];
#pragma unroll
  for (int tt = 0; tt < 16; ++tt) { acc0[tt] = 0.f; acc1[tt] = 0.f; }

  for (int k0 = 0; k0 < 1024; k0 += 4) {
    float4 w0v, w1v;
    w0v.x = fcwT[(k0 + 0) * 512 + tid];       w1v.x = fcwT[(k0 + 0) * 512 + 256 + tid];
    w0v.y = fcwT[(k0 + 1) * 512 + tid];       w1v.y = fcwT[(k0 + 1) * 512 + 256 + tid];
    w0v.z = fcwT[(k0 + 2) * 512 + tid];       w1v.z = fcwT[(k0 + 2) * 512 + 256 + tid];
    w0v.w = fcwT[(k0 + 3) * 512 + tid];       w1v.w = fcwT[(k0 + 3) * 512 + 256 + tid];
    float4 hv[16];
#pragma unroll
    for (int tt = 0; tt < 16; ++tt) hv[tt] = *(const float4*)&smem[tt * 1024 + k0];
#pragma unroll
    for (int tt = 0; tt < 16; ++tt) {
      acc0[tt] += dot4f(w0v, hv[tt]);
      acc1[tt] += dot4f(w1v, hv[tt]);
    }
  }
  float bb0 = fcb[tid], bb1 = fcb[tid + 256];
  __syncthreads();  // done reading h1 tile; alias smem as logits [16][512]
#pragma unroll
  for (int tt = 0; tt < 16; ++tt) {
    smem[tt * 512 + tid] = acc0[tt] + bb0;
    smem[tt * 512 + 256 + tid] = acc1[tt] + bb1;
  }
  __syncthreads();

  const int wv = tid >> 6, l = tid & 63;
  for (int r = 0; r < 4; ++r) {
    int tt = wv * 4 + r;
    float v[8];
    float mx = -3.4e38f;
#pragma unroll
    for (int m = 0; m < 8; ++m) { v[m] = smem[tt * 512 + m * 64 + l]; mx = fmaxf(mx, v[m]); }
#pragma unroll
    for (int s = 1; s < 64; s <<= 1) mx = fmaxf(mx, __shfl_xor(mx, s, 64));
    float sum = 0.f;
#pragma unroll
    for (int m = 0; m < 8; ++m) { v[m] = expf(v[m] - mx); sum += v[m]; }
#pragma unroll
    for (int s = 1; s < 64; s <<= 1) sum += __shfl_xor(sum, s, 64);
    float inv = 1.0f / sum;
#pragma unroll
    for (int m = 0; m < 8; ++m) out[(size_t)(t0 + tt) * 512 + m * 64 + l] = v[m] * inv;
  }
}

extern "C" void kernel_launch(void* const* d_in, const int* in_sizes, int n_in,
                              void* d_out, int out_size, void* d_ws, size_t ws_size,
                              hipStream_t stream) {
  const float* x    = (const float*)d_in[0];
  const float* Wih0 = (const float*)d_in[1];
  const float* Whh0 = (const float*)d_in[2];
  const float* bih0 = (const float*)d_in[3];
  const float* bhh0 = (const float*)d_in[4];
  const float* Wih1 = (const float*)d_in[5];
  const float* Whh1 = (const float*)d_in[6];
  const float* bih1 = (const float*)d_in[7];
  const float* bhh1 = (const float*)d_in[8];
  const float* h0in = (const float*)d_in[9];
  const float* c0in = (const float*)d_in[10];
  const float* fcw  = (const float*)d_in[11];
  const float* fcb  = (const float*)d_in[12];
  float* out = (float*)d_out;

  // workspace: h0buf (B slots) | h1buf (B+1 slots) | fcwT  -> ~69 MB
  u64* h0buf = (u64*)d_ws;
  u64* h1buf = h0buf + (size_t)LSTM_B * 1024;
  float* fcwT = (float*)(h1buf + (size_t)(LSTM_B + 1) * 1024);

  hipLaunchKernelGGL(k_transpose, dim3((512 * 1024) / 256), dim3(256), 0, stream, fcw, fcwT);
  hipLaunchKernelGGL(k_recur, dim3(256), dim3(512), 0, stream,
                     x, Whh0, Wih0, bih0, bhh0, Wih1, Whh1, bih1, bhh1,
                     h0in, c0in, h0buf, h1buf);
  hipLaunchKernelGGL(k_fc, dim3(LSTM_B / 16), dim3(256), 0, stream, h1buf, fcwT, fcb, out);
}

// Round 5
// 16978.615 us; speedup vs baseline: 1.2511x; 1.2511x over previous
//
#include <hip/hip_runtime.h>

#define LSTM_B   4096
#define LSTM_H   1024
#define LSTM_IN  512
#define LSTM_OUT 512

typedef unsigned long long u64;
typedef unsigned int u32;

__device__ __forceinline__ u64 aload(u64* p) {
  return __hip_atomic_load(p, __ATOMIC_RELAXED, __HIP_MEMORY_SCOPE_AGENT);
}
__device__ __forceinline__ void astore(u64* p, u64 v) {
  __hip_atomic_store(p, v, __ATOMIC_RELAXED, __HIP_MEMORY_SCOPE_AGENT);
}
__device__ __forceinline__ u64 packft(float f, u32 tag) {
  return ((u64)tag << 32) | (u64)__float_as_uint(f);
}
__device__ __forceinline__ float dot4f(float4 a, float4 b) {
  return fmaf(a.x, b.x, fmaf(a.y, b.y, fmaf(a.z, b.z, a.w * b.w)));
}
// fast activations: v_exp_f32 + v_rcp_f32. |rel err| ~1e-6, bounded outputs.
__device__ __forceinline__ float fsig(float x) {
  return __builtin_amdgcn_rcpf(1.0f + __expf(-x));
}
__device__ __forceinline__ float ftanh(float x) {
  return 1.0f - 2.0f * __builtin_amdgcn_rcpf(1.0f + __expf(2.0f * x));
}

// ---- AGPR parking: weights live in the accumulator half of the unified RF.
// park4: VGPR->AGPR once at init. fetch4: AGPR->VGPR each use, asm volatile so
// it can't be hoisted (loop-invariant!) or turned back into a memory load.
__device__ __forceinline__ void park4(float4& a, float4 v) {
  asm volatile("v_accvgpr_write_b32 %0, %4\n\t"
               "v_accvgpr_write_b32 %1, %5\n\t"
               "v_accvgpr_write_b32 %2, %6\n\t"
               "v_accvgpr_write_b32 %3, %7"
               : "=a"(a.x), "=a"(a.y), "=a"(a.z), "=a"(a.w)
               : "v"(v.x), "v"(v.y), "v"(v.z), "v"(v.w));
}
__device__ __forceinline__ float4 fetch4(const float4& a) {
  float4 r;
  asm volatile("v_accvgpr_read_b32 %0, %4\n\t"
               "v_accvgpr_read_b32 %1, %5\n\t"
               "v_accvgpr_read_b32 %2, %6\n\t"
               "v_accvgpr_read_b32 %3, %7"
               : "=v"(r.x), "=v"(r.y), "=v"(r.z), "=v"(r.w)
               : "a"(a.x), "a"(a.y), "a"(a.z), "a"(a.w));
  return r;
}

// ---------------- transpose fc_w [512,1024] -> fcwT [1024,512] ----------------
__global__ void k_transpose(const float* __restrict__ w, float* __restrict__ wT) {
  int idx = blockIdx.x * 256 + threadIdx.x;   // 512*1024 total
  int k = idx >> 9;
  int o = idx & 511;
  wT[idx] = w[o * 1024 + k];
}

// ---------------- persistent recurrent kernel ----------------
// 256 blocks x 512 threads (8 waves, 2/SIMD). Block bx owns units 4bx..4bx+3.
// Waves 0-3: layer1 unit j=w -> 128 weight floats in AGPRs.
// Waves 4-7: layer0 unit j=w-4 -> 96 weight floats in AGPRs.
// Incremental tag-polling: each of a thread's 4 slots is re-loaded only while
// its tag is stale (exec-masked), so steady-state poll traffic ~= data size
// (16 KB/block/step) instead of 16 KB per ~200ns round. s_sleep(4) backoff.
__global__ __launch_bounds__(512)
__attribute__((amdgpu_waves_per_eu(2, 2)))
void k_recur(
    const float* __restrict__ x,
    const float* __restrict__ Whh0, const float* __restrict__ Wih0,
    const float* __restrict__ bih0, const float* __restrict__ bhh0,
    const float* __restrict__ Wih1, const float* __restrict__ Whh1,
    const float* __restrict__ bih1, const float* __restrict__ bhh1,
    const float* __restrict__ h0in, const float* __restrict__ c0in,
    u64* __restrict__ h0buf, u64* __restrict__ h1buf)
{
  __shared__ float h0s[2][LSTM_H];
  __shared__ float h1s[2][LSTM_H];
  __shared__ float xs[2][LSTM_IN];

  const int tid = threadIdx.x;           // 0..511
  const int w = tid >> 6, l = tid & 63;
  const int bx = blockIdx.x;
  const int j = w & 3;
  const int hd = 4 * bx + j;

  // prologue LDS: h0 init (phase -1 uses buffer 1), x[0]
  h0s[1][tid]       = h0in[tid];
  h0s[1][tid + 512] = h0in[tid + 512];
  xs[1][tid & 511]  = x[tid & 511];

  if (w < 4) {
    // ================= layer-1 waves =================
    float4 Wi[4][4], Wh[4][4];   // AGPR-resident (park4/fetch4 only)
#pragma unroll
    for (int g = 0; g < 4; ++g)
#pragma unroll
      for (int q = 0; q < 4; ++q) {
        park4(Wi[g][q], *(const float4*)&Wih1[(size_t)(g * 1024 + hd) * 1024 + q * 256 + 4 * l]);
        park4(Wh[g][q], *(const float4*)&Whh1[(size_t)(g * 1024 + hd) * 1024 + q * 256 + 4 * l]);
      }
    float bsum[4];
#pragma unroll
    for (int g = 0; g < 4; ++g) bsum[g] = bih1[g * 1024 + hd] + bhh1[g * 1024 + hd];
    float c = c0in[1024 + hd];

    __syncthreads();  // prologue barrier (matches other branch)
    if (l == 0) astore(&h1buf[hd], packft(h0in[1024 + hd], 0u));  // seed h1(init) step 0

    u64* p0 = &h0buf[tid];
    u64* p1 = &h1buf[tid];
#pragma unroll 1
    for (int t = 0; t < LSTM_B; ++t, p0 += 1024, p1 += 1024) {
      const int buf = t & 1;
      const u32 tt = (u32)t;
      // ---- incremental poll: re-load only stale slots
      u64 v0a = 0, v0b = 0, v1a = 0, v1b = 0;
      bool d0a = false, d0b = false, d1a = false, d1b = false;
      for (;;) {
        if (!d0a) { v0a = aload(p0);       d0a = ((u32)(v0a >> 32) == tt); }
        if (!d0b) { v0b = aload(p0 + 512); d0b = ((u32)(v0b >> 32) == tt); }
        if (!d1a) { v1a = aload(p1);       d1a = ((u32)(v1a >> 32) == tt); }
        if (!d1b) { v1b = aload(p1 + 512); d1b = ((u32)(v1b >> 32) == tt); }
        if (__all(d0a && d0b && d1a && d1b)) break;
        __builtin_amdgcn_s_sleep(4);
      }
      h0s[buf][tid]       = __uint_as_float((u32)v0a);
      h0s[buf][tid + 512] = __uint_as_float((u32)v0b);
      h1s[buf][tid]       = __uint_as_float((u32)v1a);
      h1s[buf][tid + 512] = __uint_as_float((u32)v1b);
      __syncthreads();

      float a0 = 0.f, a1 = 0.f, a2 = 0.f, a3 = 0.f;
#pragma unroll
      for (int q = 0; q < 4; ++q) {
        float4 h0q = *(const float4*)&h0s[buf][q * 256 + 4 * l];
        float4 h1q = *(const float4*)&h1s[buf][q * 256 + 4 * l];
        { float4 u = fetch4(Wi[0][q]); a0 += dot4f(u, h0q); u = fetch4(Wh[0][q]); a0 += dot4f(u, h1q); }
        { float4 u = fetch4(Wi[1][q]); a1 += dot4f(u, h0q); u = fetch4(Wh[1][q]); a1 += dot4f(u, h1q); }
        { float4 u = fetch4(Wi[2][q]); a2 += dot4f(u, h0q); u = fetch4(Wh[2][q]); a2 += dot4f(u, h1q); }
        { float4 u = fetch4(Wi[3][q]); a3 += dot4f(u, h0q); u = fetch4(Wh[3][q]); a3 += dot4f(u, h1q); }
      }
#pragma unroll
      for (int m = 1; m < 64; m <<= 1) {
        a0 += __shfl_xor(a0, m, 64);
        a1 += __shfl_xor(a1, m, 64);
        a2 += __shfl_xor(a2, m, 64);
        a3 += __shfl_xor(a3, m, 64);
      }
      c = fsig(a1 + bsum[1]) * c + fsig(a0 + bsum[0]) * ftanh(a2 + bsum[2]);
      float hn = fsig(a3 + bsum[3]) * ftanh(c);
      if (l == 0) astore(&h1buf[(size_t)(t + 1) * 1024 + hd], packft(hn, tt + 1));
    }
  } else {
    // ================= layer-0 waves =================
    float4 Whr[4][4], Wxr[4][2];  // AGPR-resident
#pragma unroll
    for (int g = 0; g < 4; ++g) {
#pragma unroll
      for (int q = 0; q < 4; ++q)
        park4(Whr[g][q], *(const float4*)&Whh0[(size_t)(g * 1024 + hd) * 1024 + q * 256 + 4 * l]);
#pragma unroll
      for (int q = 0; q < 2; ++q)
        park4(Wxr[g][q], *(const float4*)&Wih0[(size_t)(g * 1024 + hd) * 512 + q * 256 + 4 * l]);
    }
    float bsum[4];
#pragma unroll
    for (int g = 0; g < 4; ++g) bsum[g] = bih0[g * 1024 + hd] + bhh0[g * 1024 + hd];
    float c = c0in[hd];

    __syncthreads();  // prologue barrier
    {
      // prologue compute: layer0 step 0 from h0 init (buffer 1) and x[0]
      float a0 = 0.f, a1 = 0.f, a2 = 0.f, a3 = 0.f;
#pragma unroll
      for (int q = 0; q < 4; ++q) {
        float4 hq = *(const float4*)&h0s[1][q * 256 + 4 * l];
        { float4 u = fetch4(Whr[0][q]); a0 += dot4f(u, hq); }
        { float4 u = fetch4(Whr[1][q]); a1 += dot4f(u, hq); }
        { float4 u = fetch4(Whr[2][q]); a2 += dot4f(u, hq); }
        { float4 u = fetch4(Whr[3][q]); a3 += dot4f(u, hq); }
      }
#pragma unroll
      for (int q = 0; q < 2; ++q) {
        float4 xq = *(const float4*)&xs[1][q * 256 + 4 * l];
        { float4 u = fetch4(Wxr[0][q]); a0 += dot4f(u, xq); }
        { float4 u = fetch4(Wxr[1][q]); a1 += dot4f(u, xq); }
        { float4 u = fetch4(Wxr[2][q]); a2 += dot4f(u, xq); }
        { float4 u = fetch4(Wxr[3][q]); a3 += dot4f(u, xq); }
      }
#pragma unroll
      for (int m = 1; m < 64; m <<= 1) {
        a0 += __shfl_xor(a0, m, 64);
        a1 += __shfl_xor(a1, m, 64);
        a2 += __shfl_xor(a2, m, 64);
        a3 += __shfl_xor(a3, m, 64);
      }
      c = fsig(a1 + bsum[1]) * c + fsig(a0 + bsum[0]) * ftanh(a2 + bsum[2]);
      float hn = fsig(a3 + bsum[3]) * ftanh(c);
      if (l == 0) astore(&h0buf[hd], packft(hn, 0u));
    }

    const int xi = tid - 256;  // 0..255
    u64* p0 = &h0buf[tid];
    u64* p1 = &h1buf[tid];
#pragma unroll 1
    for (int t = 0; t < LSTM_B; ++t, p0 += 1024, p1 += 1024) {
      const int buf = t & 1;
      const u32 tt = (u32)t;
      // x(t+1) prefetch issued before polling (latency hidden by poll)
      float xv0 = 0.f, xv1 = 0.f;
      if (t + 1 < LSTM_B) {
        xv0 = x[(size_t)(t + 1) * 512 + xi];
        xv1 = x[(size_t)(t + 1) * 512 + xi + 256];
      }
      u64 v0a = 0, v0b = 0, v1a = 0, v1b = 0;
      bool d0a = false, d0b = false, d1a = false, d1b = false;
      for (;;) {
        if (!d0a) { v0a = aload(p0);       d0a = ((u32)(v0a >> 32) == tt); }
        if (!d0b) { v0b = aload(p0 + 512); d0b = ((u32)(v0b >> 32) == tt); }
        if (!d1a) { v1a = aload(p1);       d1a = ((u32)(v1a >> 32) == tt); }
        if (!d1b) { v1b = aload(p1 + 512); d1b = ((u32)(v1b >> 32) == tt); }
        if (__all(d0a && d0b && d1a && d1b)) break;
        __builtin_amdgcn_s_sleep(4);
      }
      h0s[buf][tid]       = __uint_as_float((u32)v0a);
      h0s[buf][tid + 512] = __uint_as_float((u32)v0b);
      h1s[buf][tid]       = __uint_as_float((u32)v1a);
      h1s[buf][tid + 512] = __uint_as_float((u32)v1b);
      xs[buf][xi]         = xv0;
      xs[buf][xi + 256]   = xv1;
      __syncthreads();

      float a0 = 0.f, a1 = 0.f, a2 = 0.f, a3 = 0.f;
#pragma unroll
      for (int q = 0; q < 4; ++q) {
        float4 hq = *(const float4*)&h0s[buf][q * 256 + 4 * l];
        { float4 u = fetch4(Whr[0][q]); a0 += dot4f(u, hq); }
        { float4 u = fetch4(Whr[1][q]); a1 += dot4f(u, hq); }
        { float4 u = fetch4(Whr[2][q]); a2 += dot4f(u, hq); }
        { float4 u = fetch4(Whr[3][q]); a3 += dot4f(u, hq); }
      }
#pragma unroll
      for (int q = 0; q < 2; ++q) {
        float4 xq = *(const float4*)&xs[buf][q * 256 + 4 * l];
        { float4 u = fetch4(Wxr[0][q]); a0 += dot4f(u, xq); }
        { float4 u = fetch4(Wxr[1][q]); a1 += dot4f(u, xq); }
        { float4 u = fetch4(Wxr[2][q]); a2 += dot4f(u, xq); }
        { float4 u = fetch4(Wxr[3][q]); a3 += dot4f(u, xq); }
      }
#pragma unroll
      for (int m = 1; m < 64; m <<= 1) {
        a0 += __shfl_xor(a0, m, 64);
        a1 += __shfl_xor(a1, m, 64);
        a2 += __shfl_xor(a2, m, 64);
        a3 += __shfl_xor(a3, m, 64);
      }
      c = fsig(a1 + bsum[1]) * c + fsig(a0 + bsum[0]) * ftanh(a2 + bsum[2]);
      float hn = fsig(a3 + bsum[3]) * ftanh(c);
      if (l == 0 && t + 1 < LSTM_B)
        astore(&h0buf[(size_t)(t + 1) * 1024 + hd], packft(hn, tt + 1));
    }
  }
}

// ---------------- FC + softmax: 16 timesteps per block ----------------
__global__ __launch_bounds__(256) void k_fc(u64* __restrict__ h1buf,
                                            const float* __restrict__ fcwT,
                                            const float* __restrict__ fcb,
                                            float* __restrict__ out) {
  __shared__ float smem[16 * 1024];
  const int tid = threadIdx.x;
  const int t0 = blockIdx.x * 16;

  for (int i = 0; i < 64; ++i) {
    int e = tid + 256 * i;
    int tt = e >> 10, k = e & 1023;
    u64 v = aload(&h1buf[(size_t)(t0 + tt + 1) * 1024 + k]);
    smem[e] = __uint_as_float((u32)v);
  }
  __syncthreads();

  float acc0[16], acc1[16];
#pragma unroll
  for (int tt = 0; tt < 16; ++tt) { acc0[tt] = 0.f; acc1[tt] = 0.f; }

  for (int k0 = 0; k0 < 1024; k0 += 4) {
    float4 w0v, w1v;
    w0v.x = fcwT[(k0 + 0) * 512 + tid];       w1v.x = fcwT[(k0 + 0) * 512 + 256 + tid];
    w0v.y = fcwT[(k0 + 1) * 512 + tid];       w1v.y = fcwT[(k0 + 1) * 512 + 256 + tid];
    w0v.z = fcwT[(k0 + 2) * 512 + tid];       w1v.z = fcwT[(k0 + 2) * 512 + 256 + tid];
    w0v.w = fcwT[(k0 + 3) * 512 + tid];       w1v.w = fcwT[(k0 + 3) * 512 + 256 + tid];
    float4 hv[16];
#pragma unroll
    for (int tt = 0; tt < 16; ++tt) hv[tt] = *(const float4*)&smem[tt * 1024 + k0];
#pragma unroll
    for (int tt = 0; tt < 16; ++tt) {
      acc0[tt] += dot4f(w0v, hv[tt]);
      acc1[tt] += dot4f(w1v, hv[tt]);
    }
  }
  float bb0 = fcb[tid], bb1 = fcb[tid + 256];
  __syncthreads();  // done reading h1 tile; alias smem as logits [16][512]
#pragma unroll
  for (int tt = 0; tt < 16; ++tt) {
    smem[tt * 512 + tid] = acc0[tt] + bb0;
    smem[tt * 512 + 256 + tid] = acc1[tt] + bb1;
  }
  __syncthreads();

  const int wv = tid >> 6, l = tid & 63;
  for (int r = 0; r < 4; ++r) {
    int tt = wv * 4 + r;
    float v[8];
    float mx = -3.4e38f;
#pragma unroll
    for (int m = 0; m < 8; ++m) { v[m] = smem[tt * 512 + m * 64 + l]; mx = fmaxf(mx, v[m]); }
#pragma unroll
    for (int s = 1; s < 64; s <<= 1) mx = fmaxf(mx, __shfl_xor(mx, s, 64));
    float sum = 0.f;
#pragma unroll
    for (int m = 0; m < 8; ++m) { v[m] = expf(v[m] - mx); sum += v[m]; }
#pragma unroll
    for (int s = 1; s < 64; s <<= 1) sum += __shfl_xor(sum, s, 64);
    float inv = 1.0f / sum;
#pragma unroll
    for (int m = 0; m < 8; ++m) out[(size_t)(t0 + tt) * 512 + m * 64 + l] = v[m] * inv;
  }
}

extern "C" void kernel_launch(void* const* d_in, const int* in_sizes, int n_in,
                              void* d_out, int out_size, void* d_ws, size_t ws_size,
                              hipStream_t stream) {
  const float* x    = (const float*)d_in[0];
  const float* Wih0 = (const float*)d_in[1];
  const float* Whh0 = (const float*)d_in[2];
  const float* bih0 = (const float*)d_in[3];
  const float* bhh0 = (const float*)d_in[4];
  const float* Wih1 = (const float*)d_in[5];
  const float* Whh1 = (const float*)d_in[6];
  const float* bih1 = (const float*)d_in[7];
  const float* bhh1 = (const float*)d_in[8];
  const float* h0in = (const float*)d_in[9];
  const float* c0in = (const float*)d_in[10];
  const float* fcw  = (const float*)d_in[11];
  const float* fcb  = (const float*)d_in[12];
  float* out = (float*)d_out;

  // workspace: h0buf (B slots) | h1buf (B+1 slots) | fcwT  -> ~69 MB
  u64* h0buf = (u64*)d_ws;
  u64* h1buf = h0buf + (size_t)LSTM_B * 1024;
  float* fcwT = (float*)(h1buf + (size_t)(LSTM_B + 1) * 1024);

  hipLaunchKernelGGL(k_transpose, dim3((512 * 1024) / 256), dim3(256), 0, stream, fcw, fcwT);
  hipLaunchKernelGGL(k_recur, dim3(256), dim3(512), 0, stream,
                     x, Whh0, Wih0, bih0, bhh0, Wih1, Whh1, bih1, bhh1,
                     h0in, c0in, h0buf, h1buf);
  hipLaunchKernelGGL(k_fc, dim3(LSTM_B / 16), dim3(256), 0, stream, h1buf, fcwT, fcb, out);
}